// Round 3
// baseline (616.130 us; speedup 1.0000x reference)
//
#include <hip/hip_runtime.h>
#include <math.h>

// ---------------------------------------------------------------------------
// JKNet: 2-layer GCN (sym-norm A+I) + sum-JK + linear + log_softmax.
// Round 9: XCD-pinned feature-split gather. Evidence: gather FETCH is
// 209MB == 131B/edge == one 128B line per edge + eadj, bit-identical across
// all edge orders => per-edge fills set by per-XCD footprint (25.6MB >> 4MB
// L2), not ordering. Fix: split features in half (half-row = 128B = 1 line);
// pin half 0 to XCDs 0-3, half 1 to XCDs 4-7 via native bid%8 round-robin.
// Per-XCD footprint 25.6 -> 12.8MB => hit rate up, fills down. JK head
// un-fused into head_k (halves live on different XCDs). Also: {hist+wcast}
// and {permute+gemm1} merged into union dispatches for overlap.
// ---------------------------------------------------------------------------

#define NPAD (1 << 17)   // padded node-array stride (N=100000)
#define CHUNK 1024       // scan chunk (elements per block)

typedef __attribute__((ext_vector_type(8))) short short8;
typedef __attribute__((ext_vector_type(4))) float f32x4;

__device__ inline unsigned short f2bf(float f) {
    unsigned u = __builtin_bit_cast(unsigned, f);
    return (unsigned short)((u + 0x7fffu + ((u >> 16) & 1u)) >> 16);
}
__device__ inline float bflo(unsigned u) { return __builtin_bit_cast(float, u << 16); }
__device__ inline float bfhi(unsigned u) { return __builtin_bit_cast(float, u & 0xffff0000u); }

// ---- CSR build ------------------------------------------------------------

// Union dispatch: hist (blocks < histB) + weight cast/transpose (rest).
__global__ void mega1(const int* __restrict__ dst, int* __restrict__ cnt, int E, int histB,
                      const float* __restrict__ W1, unsigned short* __restrict__ Wt1,
                      const float* __restrict__ W2, unsigned short* __restrict__ Wt2) {
    int b = blockIdx.x;
    if (b < histB) {
        int e = b * 256 + threadIdx.x;
        if (e < E) atomicAdd(&cnt[dst[e]], 1);
    } else {
        int i = (b - histB) * 256 + threadIdx.x;
        if (i < 256 * 128) {
            int k = i >> 7, nn = i & 127;
            Wt1[nn * 256 + k] = f2bf(W1[i]);
        } else {
            int j = i - 256 * 128;
            if (j < 128 * 128) {
                int k = j >> 7, nn = j & 127;
                Wt2[nn * 128 + k] = f2bf(W2[j]);
            }
        }
    }
}

__global__ void scan_partial(const int* __restrict__ cnt, int* __restrict__ partial, int n) {
    __shared__ int sdata[4];
    int b = blockIdx.x, t = threadIdx.x;
    int base = b * CHUNK;
    int sum = 0;
    for (int i = t; i < CHUNK; i += 256) {
        int idx = base + i;
        if (idx < n) sum += cnt[idx];
    }
#pragma unroll
    for (int off = 32; off > 0; off >>= 1) sum += __shfl_down(sum, off, 64);
    if ((t & 63) == 0) sdata[t >> 6] = sum;
    __syncthreads();
    if (t == 0) partial[b] = sdata[0] + sdata[1] + sdata[2] + sdata[3];
}

// parallel exclusive scan over nblk (<=128) block sums; 1 block x 128 threads
__global__ void scan_small(int* partial, int nblk) {
    __shared__ int sm[128];
    int t = threadIdx.x;
    int v = (t < nblk) ? partial[t] : 0;
    int x = v;
    sm[t] = x;
    __syncthreads();
    for (int off = 1; off < 128; off <<= 1) {
        int y = (t >= off) ? sm[t - off] : 0;
        __syncthreads();
        x += y;
        sm[t] = x;
        __syncthreads();
    }
    if (t < nblk) partial[t] = x - v;   // exclusive
}

__global__ void scan_final(const int* __restrict__ cnt, const int* __restrict__ partial,
                           int* __restrict__ offs, int* __restrict__ cursor,
                           float* __restrict__ dis, int n) {
    __shared__ int wsum[4];
    int b = blockIdx.x, t = threadIdx.x;
    int lane = t & 63, w = t >> 6;
    int base = b * CHUNK + t * 4;
    int v[4];
#pragma unroll
    for (int j = 0; j < 4; j++) v[j] = (base + j < n) ? cnt[base + j] : 0;
    int s4 = v[0] + v[1] + v[2] + v[3];
    int inc = s4;
#pragma unroll
    for (int off = 1; off < 64; off <<= 1) {
        int x = __shfl_up(inc, off, 64);
        if (lane >= off) inc += x;
    }
    if (lane == 63) wsum[w] = inc;
    __syncthreads();
    int woff = 0;
    for (int i = 0; i < 4; i++) if (i < w) woff += wsum[i];
    int pos = partial[b] + woff + (inc - s4);
#pragma unroll
    for (int j = 0; j < 4; j++) {
        int idx = base + j;
        if (idx < n) {
            offs[idx] = pos;
            cursor[idx] = pos;
            dis[idx] = rsqrtf((float)(v[j] + 1));  // deg = incoming + self-loop
            pos += v[j];
        }
    }
}

// ---- MFMA GEMM body: Hb[n,128](bf16) = A[n,K] @ W[K,128] ------------------
template<bool ABF16>
__device__ void gemm_body(int bid, const void* __restrict__ Ap,
                          const unsigned short* __restrict__ Wt,
                          unsigned short* __restrict__ Hb,
                          int n, int K, unsigned short* bs) {
    const int tid = threadIdx.x;
    const int wave = tid >> 6, lane = tid & 63;
    const int quad = lane >> 4, mrow = lane & 15;
    const int arow_g = bid * 64 + wave * 16 + mrow;
    const int arow = arow_g < n ? arow_g : n - 1;

    f32x4 acc[8];
#pragma unroll
    for (int t = 0; t < 8; t++) acc[t] = (f32x4){0.f, 0.f, 0.f, 0.f};

    const float* Af = (const float*)Ap;
    const unsigned short* Ab = (const unsigned short*)Ap;

    for (int kc = 0; kc < K; kc += 128) {
        __syncthreads();
        for (int i = tid; i < 2048; i += 256) {
            int row = i >> 4, c8 = i & 15;
            *(short8*)&bs[row * 136 + c8 * 8] = *(const short8*)&Wt[row * K + kc + c8 * 8];
        }
        __syncthreads();
#pragma unroll
        for (int kt = 0; kt < 128; kt += 32) {
            union { short8 v; unsigned short u[8]; } A;
            if (ABF16) {
                A.v = *(const short8*)&Ab[(size_t)arow * K + kc + kt + quad * 8];
            } else {
                const float* ap = &Af[(size_t)arow * K + kc + kt + quad * 8];
                float4 p0 = *(const float4*)ap;
                float4 p1 = *(const float4*)(ap + 4);
                A.u[0] = f2bf(p0.x); A.u[1] = f2bf(p0.y);
                A.u[2] = f2bf(p0.z); A.u[3] = f2bf(p0.w);
                A.u[4] = f2bf(p1.x); A.u[5] = f2bf(p1.y);
                A.u[6] = f2bf(p1.z); A.u[7] = f2bf(p1.w);
            }
#pragma unroll
            for (int nt = 0; nt < 8; nt++) {
                short8 B = *(const short8*)&bs[(nt * 16 + mrow) * 136 + kt + quad * 8];
                acc[nt] = __builtin_amdgcn_mfma_f32_16x16x32_bf16(A.v, B, acc[nt], 0, 0, 0);
            }
        }
    }
    const int drow0 = bid * 64 + wave * 16 + quad * 4;
#pragma unroll
    for (int r = 0; r < 4; r++) {
        int dr = drow0 + r;
        if (dr < n) {
#pragma unroll
            for (int nt = 0; nt < 8; nt++)
                Hb[(size_t)dr * 128 + nt * 16 + mrow] = f2bf(acc[nt][r]);
        }
    }
}

// Union dispatch: permute (blocks < permB) + gemm layer 1 (rest). Independent.
__global__ __launch_bounds__(256) void mega2(const int* __restrict__ src,
                                             const int* __restrict__ dst,
                                             const float* __restrict__ dis,
                                             int* __restrict__ cursor,
                                             int2* __restrict__ eadj, int E, int permB,
                                             const float* __restrict__ x,
                                             const unsigned short* __restrict__ Wt1,
                                             unsigned short* __restrict__ Hb, int n) {
    __shared__ unsigned short bs[128 * 136];
    int b = blockIdx.x;
    if (b < permB) {
        int e = b * 256 + threadIdx.x;
        if (e < E) {
            int d = dst[e];
            int s = src[e];
            int pos = atomicAdd(&cursor[d], 1);
            eadj[pos] = make_int2(s, __float_as_int(dis[s] * dis[d]));
        }
    } else {
        gemm_body<false>(b - permB, x, Wt1, Hb, n, 256, bs);
    }
}

__global__ __launch_bounds__(256) void gemm2_k(const unsigned short* __restrict__ X1b,
                                               const unsigned short* __restrict__ Wt2,
                                               unsigned short* __restrict__ Hb, int n) {
    __shared__ unsigned short bs[128 * 136];
    gemm_body<true>(blockIdx.x, X1b, Wt2, Hb, n, 128, bs);
}

// ---- CSR gather, half-feature, XCD-pinned ---------------------------------
// Block decode: xcd = bid%8 (native round-robin); half = xcd>>2 selects
// features [half*64, half*64+64); nb = (bid>>3)*4 + (xcd&3) is the node-block.
// Wave = 1 node. lane = grp*8 + fl: 8 edge-groups x 8 feature-lanes; a group's
// 8 lanes read one 128B half-row (exactly one cache line). Pipeline depth-2,
// 16 edges per stage, 4 shuffles per stage (half the VALU/edge of full-row).
__global__ __launch_bounds__(256) void gather_h(const unsigned short* __restrict__ Hb,
                                                const int2* __restrict__ eadj,
                                                const int* __restrict__ offs,
                                                const int* __restrict__ cnt,
                                                const float* __restrict__ dis,
                                                const float* __restrict__ bias,
                                                unsigned short* __restrict__ outb,
                                                int n) {
    const int b = blockIdx.x;
    const int xcd = b & 7;
    const int half = xcd >> 2;
    const int nb = ((b >> 3) << 2) | (xcd & 3);
    const int w = threadIdx.x >> 6, lane = threadIdx.x & 63;
    const int grp = lane >> 3, fl = lane & 7;
    const int node = nb * 4 + w;
    const int nd = node < n ? node : n - 1;
    const int st = offs[nd], c = cnt[nd];
    const unsigned short* Hfl = Hb + half * 64 + fl * 8;

    float acc[8];
#pragma unroll
    for (int k = 0; k < 8; k++) acc[k] = 0.f;

    const int2* ep = eadj + st;
    for (int kk = 0; kk < c; kk += 64) {
        int li = kk + lane;
        int2 me = ep[li < c ? li : c - 1];             // c>0 guaranteed in loop
        float mw = li < c ? __int_as_float(me.y) : 0.f;
        int cend = (c - kk) < 64 ? (c - kk) : 64;

        // prologue: edges grp / 8+grp
        int   s0 = __shfl(me.x, grp, 64);
        float w0 = __shfl(mw,  grp, 64);
        int   s1 = __shfl(me.x, 8 + grp, 64);
        float w1 = __shfl(mw,  8 + grp, 64);
        uint4 r0 = *(const uint4*)(Hfl + (size_t)s0 * 128);
        uint4 r1 = *(const uint4*)(Hfl + (size_t)s1 * 128);

        for (int j = 0; j < cend; j += 16) {
            int jn = (j + 16 < cend) ? j + 16 : j;     // wave-uniform select
            int   sn0 = __shfl(me.x, jn + grp, 64);
            float wn0 = __shfl(mw,  jn + grp, 64);
            int   sn1 = __shfl(me.x, jn + 8 + grp, 64);
            float wn1 = __shfl(mw,  jn + 8 + grp, 64);
            uint4 rn0 = *(const uint4*)(Hfl + (size_t)sn0 * 128);  // issued before
            uint4 rn1 = *(const uint4*)(Hfl + (size_t)sn1 * 128);  // consuming r0/r1
            acc[0] = fmaf(bflo(r0.x), w0, acc[0]); acc[1] = fmaf(bfhi(r0.x), w0, acc[1]);
            acc[2] = fmaf(bflo(r0.y), w0, acc[2]); acc[3] = fmaf(bfhi(r0.y), w0, acc[3]);
            acc[4] = fmaf(bflo(r0.z), w0, acc[4]); acc[5] = fmaf(bfhi(r0.z), w0, acc[5]);
            acc[6] = fmaf(bflo(r0.w), w0, acc[6]); acc[7] = fmaf(bfhi(r0.w), w0, acc[7]);
            acc[0] = fmaf(bflo(r1.x), w1, acc[0]); acc[1] = fmaf(bfhi(r1.x), w1, acc[1]);
            acc[2] = fmaf(bflo(r1.y), w1, acc[2]); acc[3] = fmaf(bfhi(r1.y), w1, acc[3]);
            acc[4] = fmaf(bflo(r1.z), w1, acc[4]); acc[5] = fmaf(bfhi(r1.z), w1, acc[5]);
            acc[6] = fmaf(bflo(r1.w), w1, acc[6]); acc[7] = fmaf(bfhi(r1.w), w1, acc[7]);
            r0 = rn0; r1 = rn1; w0 = wn0; w1 = wn1;
        }
    }
    // reduce across the 8 edge-groups
#pragma unroll
    for (int k = 0; k < 8; k++) {
        acc[k] += __shfl_xor(acc[k], 8, 64);
        acc[k] += __shfl_xor(acc[k], 16, 64);
        acc[k] += __shfl_xor(acc[k], 32, 64);
    }
    // self-loop + bias + relu (8 contiguous features per fl-lane, this half)
    float dd = dis[nd], sn = dd * dd;
    uint4 rs = *(const uint4*)(Hfl + (size_t)nd * 128);
    float4 bb0 = ((const float4*)bias)[half * 16 + fl * 2];
    float4 bb1 = ((const float4*)bias)[half * 16 + fl * 2 + 1];
    acc[0] = fmaf(bflo(rs.x), sn, acc[0]) + bb0.x;
    acc[1] = fmaf(bfhi(rs.x), sn, acc[1]) + bb0.y;
    acc[2] = fmaf(bflo(rs.y), sn, acc[2]) + bb0.z;
    acc[3] = fmaf(bfhi(rs.y), sn, acc[3]) + bb0.w;
    acc[4] = fmaf(bflo(rs.z), sn, acc[4]) + bb1.x;
    acc[5] = fmaf(bfhi(rs.z), sn, acc[5]) + bb1.y;
    acc[6] = fmaf(bflo(rs.w), sn, acc[6]) + bb1.z;
    acc[7] = fmaf(bfhi(rs.w), sn, acc[7]) + bb1.w;
#pragma unroll
    for (int k = 0; k < 8; k++) acc[k] = acc[k] > 0.f ? acc[k] : 0.f;

    if (node < n && grp == 0) {
        uint4 pk;
        pk.x = ((unsigned)f2bf(acc[1]) << 16) | (unsigned)f2bf(acc[0]);
        pk.y = ((unsigned)f2bf(acc[3]) << 16) | (unsigned)f2bf(acc[2]);
        pk.z = ((unsigned)f2bf(acc[5]) << 16) | (unsigned)f2bf(acc[4]);
        pk.w = ((unsigned)f2bf(acc[7]) << 16) | (unsigned)f2bf(acc[6]);
        *(uint4*)(outb + (size_t)node * 128 + half * 64 + fl * 8) = pk;
    }
}

// ---- JK head: out = log_softmax((x1+x2) @ lw + lb) ------------------------
// Block = 4 waves = 4 nodes. Wave stages its node's 128 summed features in
// LDS (each lane 2 feats), then lanes<41 do the 128-dot + softmax.
__global__ __launch_bounds__(256) void head_k(const unsigned short* __restrict__ x1b,
                                              const unsigned short* __restrict__ x2b,
                                              const float* __restrict__ lw,
                                              const float* __restrict__ lb,
                                              float* __restrict__ out, int n) {
    __shared__ float s[4][128];
    const int w = threadIdx.x >> 6, lane = threadIdx.x & 63;
    const int node = blockIdx.x * 4 + w;
    const int nd = node < n ? node : n - 1;
    unsigned u1 = *(const unsigned*)(x1b + (size_t)nd * 128 + lane * 2);
    unsigned u2 = *(const unsigned*)(x2b + (size_t)nd * 128 + lane * 2);
    s[w][lane * 2]     = bflo(u1) + bflo(u2);
    s[w][lane * 2 + 1] = bfhi(u1) + bfhi(u2);
    // same-wave LDS write->read; compiler inserts lgkmcnt wait
    bool act = (node < n) && (lane < 41);
    float val = 0.f;
    if (act) {
#pragma unroll 4
        for (int f = 0; f < 128; f++) val = fmaf(s[w][f], lw[f * 41 + lane], val);
        val += lb[lane];
    }
    float m = act ? val : -INFINITY;
#pragma unroll
    for (int off = 32; off > 0; off >>= 1) m = fmaxf(m, __shfl_xor(m, off, 64));
    float e = act ? expf(val - m) : 0.f;
#pragma unroll
    for (int off = 32; off > 0; off >>= 1) e += __shfl_xor(e, off, 64);
    if (act) out[(size_t)node * 41 + lane] = val - m - logf(e);
}

extern "C" void kernel_launch(void* const* d_in, const int* in_sizes, int n_in,
                              void* d_out, int out_size, void* d_ws, size_t ws_size,
                              hipStream_t stream) {
    const float* x  = (const float*)d_in[0];
    const int*   ei = (const int*)d_in[1];
    const float* W1 = (const float*)d_in[2];
    const float* b1 = (const float*)d_in[3];
    const float* W2 = (const float*)d_in[4];
    const float* b2 = (const float*)d_in[5];
    const float* lw = (const float*)d_in[6];
    const float* lb = (const float*)d_in[7];
    float* out = (float*)d_out;

    const int n = in_sizes[0] / 256;   // 100000
    const int E = in_sizes[1] / 2;     // 1600000
    const int* src = ei;
    const int* dst = ei + E;

    // workspace layout (~92 MB)
    int*   cnt     = (int*)d_ws;                       // NPAD
    int*   offs    = cnt + NPAD;                       // NPAD
    int*   cursor  = offs + NPAD;                      // NPAD
    int*   partial = cursor + NPAD;                    // 1024
    float* dis     = (float*)(partial + 1024);         // NPAD
    size_t Epad    = ((size_t)E + 255) & ~(size_t)255;
    int2*  eadj    = (int2*)(dis + NPAD);              // Epad pairs (8 B)
    unsigned short* Wt1 = (unsigned short*)(eadj + Epad);  // 256*128 bf16
    unsigned short* Wt2 = Wt1 + 256 * 128;                 // 128*128 bf16
    unsigned short* Hb  = Wt2 + 128 * 128;                 // n*128 bf16
    unsigned short* X1b = Hb + (size_t)n * 128;            // n*128 bf16
    unsigned short* X2b = X1b + (size_t)n * 128;           // n*128 bf16

    const int nscan = (n + CHUNK - 1) / CHUNK;
    const int histB = (E + 255) / 256;                 // 6250
    const int wcastB = (256 * 128 + 128 * 128 + 255) / 256;  // 192
    const int permB = histB;
    const int gemmB = (n + 63) / 64;                   // 1563
    const int NB = (n + 3) / 4;                        // node-blocks (4/block)
    const int gathB = 8 * ((NB + 3) / 4);              // 8 XCD-combos

    hipMemsetAsync(cnt, 0, (size_t)n * sizeof(int), stream);

    // CSR hist + weight cast (independent, one dispatch)
    mega1<<<histB + wcastB, 256, 0, stream>>>(dst, cnt, E, histB, W1, Wt1, W2, Wt2);
    scan_partial<<<nscan, 256, 0, stream>>>(cnt, partial, n);
    scan_small<<<1, 128, 0, stream>>>(partial, nscan);
    scan_final<<<nscan, 256, 0, stream>>>(cnt, partial, offs, cursor, dis, n);

    // permute + gemm layer 1 (independent, one dispatch)
    mega2<<<permB + gemmB, 256, 0, stream>>>(src, dst, dis, cursor, eadj, E, permB,
                                             x, Wt1, Hb, n);

    // layer 1 aggregate (feature-split, XCD-pinned)
    gather_h<<<gathB, 256, 0, stream>>>(Hb, eadj, offs, cnt, dis, b1, X1b, n);

    // layer 2 transform + aggregate
    gemm2_k<<<gemmB, 256, 0, stream>>>(X1b, Wt2, Hb, n);
    gather_h<<<gathB, 256, 0, stream>>>(Hb, eadj, offs, cnt, dis, b2, X2b, n);

    // JK + linear + log_softmax
    head_k<<<NB, 256, 0, stream>>>(X1b, X2b, lw, lb, out, n);
}